// Round 8
// baseline (916.084 us; speedup 1.0000x reference)
//
#include <hip/hip_runtime.h>
#include <math.h>

#define NN 50000
#define NE 800000
#define INC 32
#define HIDC 64
#define OUTC 8
#define NT_TILES ((NN + 63) / 64)      // 782
#define NPAD (NT_TILES * 64)           // 50048 padded rows
#define BS 1024                        // dsts per bucket (one block owns one bucket)
#define NBK ((NN + BS - 1) / BS)       // 49

__device__ __forceinline__ float gelu_exact(float x){
    return 0.5f * x * (1.0f + erff(x * 0.70710678118654752f));
}

// accumulate out[j] += In[lane][kc*16+kk] * W[kc*16+kk][fbase+j], W stride HIDC
// fbase MUST be SGPR-uniform (readfirstlane'd) so W reads become s_load.
template<int NCH>
__device__ __forceinline__ void gemm_acc(const float* __restrict__ inrow,
                                         const float* __restrict__ W,
                                         int fbase, float out[16]){
    #pragma unroll 2
    for (int kc = 0; kc < NCH; kc++){
        float4 q0 = *(const float4*)(inrow + kc*16 + 0);
        float4 q1 = *(const float4*)(inrow + kc*16 + 4);
        float4 q2 = *(const float4*)(inrow + kc*16 + 8);
        float4 q3 = *(const float4*)(inrow + kc*16 + 12);
        float in16[16] = {q0.x,q0.y,q0.z,q0.w, q1.x,q1.y,q1.z,q1.w,
                          q2.x,q2.y,q2.z,q2.w, q3.x,q3.y,q3.z,q3.w};
        #pragma unroll
        for (int kk = 0; kk < 16; kk++){
            const float* wr = W + (size_t)(kc*16+kk)*HIDC + fbase;
            #pragma unroll
            for (int j = 0; j < 16; j++)
                out[j] = fmaf(in16[kk], wr[j], out[j]);
        }
    }
}

// ---- CSR build: single-writer buckets (49 blocks x 1024 threads) ----
// Block bk owns dst range [bk*1024, bk*1024+1024): LDS histogram + LDS scan.
// No global atomics; deg never materialized.
__global__ __launch_bounds__(1024) void k_histscan(
    const int* __restrict__ dst, int* __restrict__ loc,
    int* __restrict__ bsum, float* __restrict__ inv_deg)
{
    __shared__ int hcnt[BS];
    int bk = blockIdx.x, tid = threadIdx.x;
    hcnt[tid] = 0;
    __syncthreads();
    int lo = bk*BS, hi = lo + BS;
    for (int i = tid; i < NE; i += BS){
        int d = dst[i];
        if (d >= lo && d < hi) atomicAdd(&hcnt[d - lo], 1);
    }
    __syncthreads();
    int v = hcnt[tid];
    // in-place Hillis-Steele inclusive scan
    for (int off = 1; off < BS; off <<= 1){
        int t = (tid >= off) ? hcnt[tid - off] : 0;
        __syncthreads();
        hcnt[tid] += t;
        __syncthreads();
    }
    int g = lo + tid;
    if (g < NN){
        loc[g] = hcnt[tid] - v;              // bucket-local exclusive prefix
        inv_deg[g] = 1.0f / (float)max(v, 1);
    }
    if (tid == BS-1) bsum[bk] = hcnt[BS-1];  // bucket total
}

// exclusive scan of NBK (<=64) bucket sums, single wave; also zero dummy rows
__global__ void k_scan2(int* bsum, float* h0, float* h1){
    int tid = threadIdx.x;
    int orig = (tid < NBK) ? bsum[tid] : 0;
    int v = orig;
    for (int off = 1; off < 64; off <<= 1){
        int t = __shfl_up(v, off);
        if (tid >= off) v += t;
    }
    if (tid < NBK) bsum[tid] = v - orig;
    h0[(size_t)NN*HIDC + tid] = 0.f;         // gather target for padded edges
    h1[(size_t)NN*HIDC + tid] = 0.f;
}

// CSR fill: block bk owns its col region exclusively -> every col line is
// dirtied by ONE XCD and written back once (round-7 lesson: multi-XCD
// scattered writes to shared lines = 16x HBM write amplification).
// Cursors live in LDS; also writes row_ptr slice.
__global__ __launch_bounds__(1024) void k_fill_local(
    const int* __restrict__ src, const int* __restrict__ dst,
    const int* __restrict__ loc, const int* __restrict__ bsum,
    int* __restrict__ row_ptr, int* __restrict__ col)
{
    __shared__ int fpos[BS];
    int bk = blockIdx.x, tid = threadIdx.x;
    int lo = bk*BS, hi = lo + BS;
    int base = bsum[bk];
    int g = lo + tid;
    if (g < NN){
        int rp = loc[g] + base;
        row_ptr[g] = rp;
        fpos[tid] = rp;
    } else {
        fpos[tid] = 0;
        if (g == NN) row_ptr[NN] = NE;
    }
    __syncthreads();
    for (int i = tid; i < NE; i += BS){
        int d = dst[i];
        if (d >= lo && d < hi){
            int q = atomicAdd(&fpos[d - lo], 1);
            col[q] = src[i];
        }
    }
}

// gather-mean: one wave per node (lane = feature)
__global__ __launch_bounds__(256) void k_agg(
    const float* __restrict__ h_in,
    const int* __restrict__ row_ptr, const int* __restrict__ col,
    const float* __restrict__ inv_deg,
    float* __restrict__ agg)
{
    int tid = threadIdx.x;
    int wv = tid >> 6, f = tid & 63;
    int g = f >> 4, qoff = (f & 15) * 4;
    for (int node = blockIdx.x*4 + wv; node < NN; node += gridDim.x*4){
        int s0 = row_ptr[node], s1 = row_ptr[node+1];
        float a0 = 0.f, a1 = 0.f, a2 = 0.f, a3 = 0.f;
        for (int p0 = s0; p0 < s1; p0 += 64){
            int cnt = s1 - p0; if (cnt > 64) cnt = 64;
            int cidx = (f < cnt) ? col[p0 + f] : NN;   // NN -> zero row
            int nq = (cnt + 3) >> 2;
            for (int t = 0; t < nq; t++){
                int sidx = __shfl(cidx, t*4 + g);
                float4 v = *(const float4*)&h_in[(size_t)sidx*HIDC + qoff];
                a0 += v.x; a1 += v.y; a2 += v.z; a3 += v.w;
            }
        }
        a0 += __shfl_xor(a0, 16); a0 += __shfl_xor(a0, 32);
        a1 += __shfl_xor(a1, 16); a1 += __shfl_xor(a1, 32);
        a2 += __shfl_xor(a2, 16); a2 += __shfl_xor(a2, 32);
        a3 += __shfl_xor(a3, 16); a3 += __shfl_xor(a3, 32);
        if (g == 0){
            float idg = inv_deg[node];
            float4 o = make_float4(a0*idg, a1*idg, a2*idg, a3*idg);
            *(float4*)&agg[(size_t)node*HIDC + qoff] = o;
        }
    }
}

// ---- per-tile GEMM kernels: 256 threads = 4 waves = 4 f-chunks of one
// 64-node tile. lane = node; fb forced into SGPR via readfirstlane so
// weight reads compile to s_load (round-6 lesson: tid>>6 alone is NOT
// provably uniform -> vector loads -> VGPR 256 + scratch spill). ----

// fused encoder: h = gelu(x@w1+b1)@w2+b2, intermediate in swizzled LDS
__global__ __launch_bounds__(256) void k_enc(
    const float* __restrict__ x,
    const float* __restrict__ w1, const float* __restrict__ b1,
    const float* __restrict__ w2, const float* __restrict__ b2,
    float* __restrict__ h)
{
    __shared__ float tl[64*64];
    int tile = blockIdx.x;
    int tid = threadIdx.x, lane = tid & 63;
    int fb = __builtin_amdgcn_readfirstlane((tid >> 6) * 16);
    int node = tile*64 + lane;
    int nc = (node < NN) ? node : (NN-1);     // x has exactly NN rows
    int sw = lane & 31;
    float out[16];
    #pragma unroll
    for (int j = 0; j < 16; j++) out[j] = b1[fb + j];
    gemm_acc<2>(x + (size_t)nc*INC, w1, fb, out);
    #pragma unroll
    for (int j = 0; j < 16; j++)
        tl[lane*64 + ((fb + j) ^ sw)] = gelu_exact(out[j]);
    __syncthreads();
    float o2[16];
    #pragma unroll
    for (int j = 0; j < 16; j++) o2[j] = b2[fb + j];
    #pragma unroll 4
    for (int k = 0; k < HIDC; k++){
        float ink = tl[lane*64 + (k ^ sw)];
        const float* wr = w2 + (size_t)k*HIDC + fb;
        #pragma unroll
        for (int j = 0; j < 16; j++) o2[j] = fmaf(ink, wr[j], o2[j]);
    }
    if (node < NN){
        float* dst = h + (size_t)node*HIDC + fb;
        #pragma unroll
        for (int j4 = 0; j4 < 4; j4++)
            *(float4*)(dst + j4*4) = make_float4(o2[j4*4+0], o2[j4*4+1],
                                                 o2[j4*4+2], o2[j4*4+3]);
    }
}

// sage GEMM: h_out = gelu(agg @ wl + h_in @ wr + b)
__global__ __launch_bounds__(256) void k_sage16(
    const float* __restrict__ h_in, const float* __restrict__ agg,
    const float* __restrict__ wl, const float* __restrict__ wr,
    const float* __restrict__ bias, float* __restrict__ h_out)
{
    int tile = blockIdx.x;
    int tid = threadIdx.x, lane = tid & 63;
    int fb = __builtin_amdgcn_readfirstlane((tid >> 6) * 16);
    int node = tile*64 + lane;                 // buffers padded to NPAD rows
    float out[16];
    #pragma unroll
    for (int j = 0; j < 16; j++) out[j] = bias[fb + j];
    gemm_acc<4>(agg  + (size_t)node*HIDC, wl, fb, out);
    gemm_acc<4>(h_in + (size_t)node*HIDC, wr, fb, out);
    if (node < NN){
        float* dst = h_out + (size_t)node*HIDC + fb;
        #pragma unroll
        for (int j4 = 0; j4 < 4; j4++){
            float4 o = make_float4(gelu_exact(out[j4*4+0]), gelu_exact(out[j4*4+1]),
                                   gelu_exact(out[j4*4+2]), gelu_exact(out[j4*4+3]));
            *(float4*)(dst + j4*4) = o;
        }
    }
}

// dec stage 1: tbuf = gelu(h @ w1 + b1)
__global__ __launch_bounds__(256) void k_dec1(
    const float* __restrict__ h, const float* __restrict__ w1,
    const float* __restrict__ b1, float* __restrict__ tbuf)
{
    int tile = blockIdx.x;
    int tid = threadIdx.x, lane = tid & 63;
    int fb = __builtin_amdgcn_readfirstlane((tid >> 6) * 16);
    int node = tile*64 + lane;
    float out[16];
    #pragma unroll
    for (int j = 0; j < 16; j++) out[j] = b1[fb + j];
    gemm_acc<4>(h + (size_t)node*HIDC, w1, fb, out);
    float* dst = tbuf + (size_t)node*HIDC + fb;   // tbuf padded: unmasked
    #pragma unroll
    for (int j4 = 0; j4 < 4; j4++){
        float4 o = make_float4(gelu_exact(out[j4*4+0]), gelu_exact(out[j4*4+1]),
                               gelu_exact(out[j4*4+2]), gelu_exact(out[j4*4+3]));
        *(float4*)(dst + j4*4) = o;
    }
}

// dec stage 2: out = tbuf @ w2 + b2 (8 outputs); 4 tiles per 256-thr block
__global__ __launch_bounds__(256) void k_dec2(
    const float* __restrict__ tbuf, const float* __restrict__ w2,
    const float* __restrict__ b2, float* __restrict__ out)
{
    int tile = blockIdx.x*4 + (threadIdx.x >> 6);
    if (tile >= NT_TILES) return;              // wave-uniform branch
    int lane = threadIdx.x & 63;
    int node = tile*64 + lane;
    const float* inrow = tbuf + (size_t)node*HIDC;
    float o[OUTC];
    #pragma unroll
    for (int j = 0; j < OUTC; j++) o[j] = b2[j];
    #pragma unroll 2
    for (int kc = 0; kc < 4; kc++){
        float4 q0 = *(const float4*)(inrow + kc*16 + 0);
        float4 q1 = *(const float4*)(inrow + kc*16 + 4);
        float4 q2 = *(const float4*)(inrow + kc*16 + 8);
        float4 q3 = *(const float4*)(inrow + kc*16 + 12);
        float in16[16] = {q0.x,q0.y,q0.z,q0.w, q1.x,q1.y,q1.z,q1.w,
                          q2.x,q2.y,q2.z,q2.w, q3.x,q3.y,q3.z,q3.w};
        #pragma unroll
        for (int kk = 0; kk < 16; kk++){
            const float* wr = w2 + (size_t)(kc*16+kk)*OUTC;
            #pragma unroll
            for (int j = 0; j < OUTC; j++)
                o[j] = fmaf(in16[kk], wr[j], o[j]);
        }
    }
    if (node < NN){
        *(float4*)(out + (size_t)node*OUTC + 0) = make_float4(o[0],o[1],o[2],o[3]);
        *(float4*)(out + (size_t)node*OUTC + 4) = make_float4(o[4],o[5],o[6],o[7]);
    }
}

extern "C" void kernel_launch(void* const* d_in, const int* in_sizes, int n_in,
                              void* d_out, int out_size, void* d_ws, size_t ws_size,
                              hipStream_t stream){
    const float* x      = (const float*)d_in[0];
    const int*   ei     = (const int*)  d_in[1];
    const float* enc_w1 = (const float*)d_in[2];
    const float* enc_b1 = (const float*)d_in[3];
    const float* enc_w2 = (const float*)d_in[4];
    const float* enc_b2 = (const float*)d_in[5];
    const float* sage_wl= (const float*)d_in[6];
    const float* sage_wr= (const float*)d_in[7];
    const float* sage_b = (const float*)d_in[8];
    const float* dec_w1 = (const float*)d_in[9];
    const float* dec_b1 = (const float*)d_in[10];
    const float* dec_w2 = (const float*)d_in[11];
    const float* dec_b2 = (const float*)d_in[12];
    float* out = (float*)d_out;

    char* ws = (char*)d_ws;
    size_t off = 0;
    auto alloc = [&](size_t bytes)->void*{
        void* p = ws + off; off = (off + bytes + 255) & ~(size_t)255; return p;
    };
    int*   loc      = (int*)  alloc((size_t)NN*4);
    int*   bsum     = (int*)  alloc(64*4);
    int*   row_ptr  = (int*)  alloc((size_t)(NN+1)*4);
    int*   col      = (int*)  alloc((size_t)NE*4);
    float* inv_deg  = (float*)alloc((size_t)NN*4);
    float* h0       = (float*)alloc((size_t)NPAD*HIDC*4);
    float* h1       = (float*)alloc((size_t)NPAD*HIDC*4);
    float* agg      = (float*)alloc((size_t)NPAD*HIDC*4);  // doubles as tbuf

    const int* srcv = ei;        // edge_index row 0
    const int* dstv = ei + NE;   // edge_index row 1

    hipLaunchKernelGGL(k_histscan,   dim3(NBK), dim3(BS), 0, stream,
                       dstv, loc, bsum, inv_deg);
    hipLaunchKernelGGL(k_scan2,      dim3(1),   dim3(64), 0, stream,
                       bsum, h0, h1);
    hipLaunchKernelGGL(k_fill_local, dim3(NBK), dim3(BS), 0, stream,
                       srcv, dstv, loc, bsum, row_ptr, col);

    hipLaunchKernelGGL(k_enc, dim3(NT_TILES), dim3(256), 0, stream,
                       x, enc_w1, enc_b1, enc_w2, enc_b2, h0);

    const float* hin = h0; float* hout = h1;
    for (int l = 0; l < 3; l++){
        hipLaunchKernelGGL(k_agg, dim3(2048), dim3(256), 0, stream,
                           hin, row_ptr, col, inv_deg, agg);
        hipLaunchKernelGGL(k_sage16, dim3(NT_TILES), dim3(256), 0, stream,
                           hin, agg,
                           sage_wl + (size_t)l*HIDC*HIDC,
                           sage_wr + (size_t)l*HIDC*HIDC,
                           sage_b  + (size_t)l*HIDC,
                           hout);
        float* t = (float*)hin; hin = hout; hout = t;
    }

    hipLaunchKernelGGL(k_dec1, dim3(NT_TILES),       dim3(256), 0, stream,
                       hin, dec_w1, dec_b1, agg);
    hipLaunchKernelGGL(k_dec2, dim3((NT_TILES+3)/4), dim3(256), 0, stream,
                       agg, dec_w2, dec_b2, out);
}

// Round 9
// 418.707 us; speedup vs baseline: 2.1879x; 2.1879x over previous
//
#include <hip/hip_runtime.h>
#include <math.h>

#define NN 50000
#define NE 800000
#define INC 32
#define HIDC 64
#define OUTC 8
#define NB_SCAN ((NN + 1023) / 1024)   // 49
#define NT_TILES ((NN + 63) / 64)      // 782
#define NPAD (NT_TILES * 64)           // 50048 padded rows
#define NXCD 8
#define PCH 32                          // edge chunks per partition
#define PSZ ((NN + NXCD - 1) / NXCD)    // 6250 dsts per partition
#define ECH (NE / PCH)                  // 25000 edges per chunk (4-aligned)

__device__ __forceinline__ float gelu_exact(float x){
    return 0.5f * x * (1.0f + erff(x * 0.70710678118654752f));
}

// accumulate out[j] += In[lane][kc*16+kk] * W[kc*16+kk][fbase+j], W stride HIDC
// fbase MUST be SGPR-uniform (readfirstlane'd) so W reads become s_load.
template<int NCH>
__device__ __forceinline__ void gemm_acc(const float* __restrict__ inrow,
                                         const float* __restrict__ W,
                                         int fbase, float out[16]){
    #pragma unroll 2
    for (int kc = 0; kc < NCH; kc++){
        float4 q0 = *(const float4*)(inrow + kc*16 + 0);
        float4 q1 = *(const float4*)(inrow + kc*16 + 4);
        float4 q2 = *(const float4*)(inrow + kc*16 + 8);
        float4 q3 = *(const float4*)(inrow + kc*16 + 12);
        float in16[16] = {q0.x,q0.y,q0.z,q0.w, q1.x,q1.y,q1.z,q1.w,
                          q2.x,q2.y,q2.z,q2.w, q3.x,q3.y,q3.z,q3.w};
        #pragma unroll
        for (int kk = 0; kk < 16; kk++){
            const float* wr = W + (size_t)(kc*16+kk)*HIDC + fbase;
            #pragma unroll
            for (int j = 0; j < 16; j++)
                out[j] = fmaf(in16[kk], wr[j], out[j]);
        }
    }
}

// ---- CSR build, XCD-affine: partition p (dst range) is touched ONLY by
// blocks with bid&7==p, which land on one XCD (round-robin placement) ->
// deg/fill_pos/col lines for p live in ONE L2, written back once.
// (rounds 5-8 lesson: cross-XCD scattered writes = 16x write amplification;
//  single-block ownership = parallelism collapse. Same-XCD ownership = both.)

__global__ __launch_bounds__(256) void k_hist_xcd(const int* __restrict__ dst,
                                                  int* __restrict__ deg){
    int p = blockIdx.x & (NXCD-1);
    int c = blockIdx.x >> 3;
    int lo = p*PSZ, hi = lo + PSZ;
    int e0 = c*ECH;
    for (int i = e0 + threadIdx.x*4; i < e0 + ECH; i += 1024){
        int4 d4 = *(const int4*)(dst + i);
        if (d4.x >= lo && d4.x < hi) atomicAdd(&deg[d4.x], 1);
        if (d4.y >= lo && d4.y < hi) atomicAdd(&deg[d4.y], 1);
        if (d4.z >= lo && d4.z < hi) atomicAdd(&deg[d4.z], 1);
        if (d4.w >= lo && d4.w < hi) atomicAdd(&deg[d4.w], 1);
    }
}

__global__ __launch_bounds__(1024) void k_scan1(const int* __restrict__ deg,
                                                int* loc, int* bsum){
    __shared__ int sd[1024];
    int b = blockIdx.x, tid = threadIdx.x, g = b*1024 + tid;
    int v = (g < NN) ? deg[g] : 0;
    sd[tid] = v;
    __syncthreads();
    for (int off = 1; off < 1024; off <<= 1){
        int t = (tid >= off) ? sd[tid-off] : 0;
        __syncthreads();
        sd[tid] += t;
        __syncthreads();
    }
    if (g < NN) loc[g] = sd[tid] - v;
    if (tid == 1023) bsum[b] = sd[1023];
}

// scan of 49 chunk sums (single wave) + zero dummy h rows
__global__ void k_scan2(int* bsum, float* h0, float* h1){
    int tid = threadIdx.x;
    int orig = (tid < NB_SCAN) ? bsum[tid] : 0;
    int v = orig;
    for (int off = 1; off < 64; off <<= 1){
        int t = __shfl_up(v, off);
        if (tid >= off) v += t;
    }
    if (tid < NB_SCAN) bsum[tid] = v - orig;
    h0[(size_t)NN*HIDC + tid] = 0.f;  h0[(size_t)NN*HIDC + 64 + tid] = 0.f;
    h1[(size_t)NN*HIDC + tid] = 0.f;  h1[(size_t)NN*HIDC + 64 + tid] = 0.f;
}

__global__ void k_scan3(const int* __restrict__ deg, const int* __restrict__ loc,
                        const int* __restrict__ bsum,
                        int* row_ptr, int* fill_pos, float* inv_deg){
    int g = blockIdx.x*blockDim.x + threadIdx.x;
    if (g < NN){
        int e = loc[g] + bsum[g >> 10];
        row_ptr[g] = e; fill_pos[g] = e;
        inv_deg[g] = 1.0f / (float)max(deg[g], 1);
    }
    if (g == 0) row_ptr[NN] = NE;
}

__global__ __launch_bounds__(256) void k_fill_xcd(
    const int* __restrict__ src, const int* __restrict__ dst,
    int* __restrict__ fill_pos, int* __restrict__ col)
{
    int p = blockIdx.x & (NXCD-1);
    int c = blockIdx.x >> 3;
    int lo = p*PSZ, hi = lo + PSZ;
    int e0 = c*ECH;
    for (int i = e0 + threadIdx.x*4; i < e0 + ECH; i += 1024){
        int4 d4 = *(const int4*)(dst + i);
        if (d4.x >= lo && d4.x < hi){ int q = atomicAdd(&fill_pos[d4.x],1); col[q] = src[i+0]; }
        if (d4.y >= lo && d4.y < hi){ int q = atomicAdd(&fill_pos[d4.y],1); col[q] = src[i+1]; }
        if (d4.z >= lo && d4.z < hi){ int q = atomicAdd(&fill_pos[d4.z],1); col[q] = src[i+2]; }
        if (d4.w >= lo && d4.w < hi){ int q = atomicAdd(&fill_pos[d4.w],1); col[q] = src[i+3]; }
    }
}

// gather-mean: one wave per node (lane = feature)
__global__ __launch_bounds__(256) void k_agg(
    const float* __restrict__ h_in,
    const int* __restrict__ row_ptr, const int* __restrict__ col,
    const float* __restrict__ inv_deg,
    float* __restrict__ agg)
{
    int tid = threadIdx.x;
    int wv = tid >> 6, f = tid & 63;
    int g = f >> 4, qoff = (f & 15) * 4;
    for (int node = blockIdx.x*4 + wv; node < NN; node += gridDim.x*4){
        int s0 = row_ptr[node], s1 = row_ptr[node+1];
        float a0 = 0.f, a1 = 0.f, a2 = 0.f, a3 = 0.f;
        for (int p0 = s0; p0 < s1; p0 += 64){
            int cnt = s1 - p0; if (cnt > 64) cnt = 64;
            int cidx = (f < cnt) ? col[p0 + f] : NN;   // NN -> zero row
            int nq = (cnt + 3) >> 2;
            for (int t = 0; t < nq; t++){
                int sidx = __shfl(cidx, t*4 + g);
                float4 v = *(const float4*)&h_in[(size_t)sidx*HIDC + qoff];
                a0 += v.x; a1 += v.y; a2 += v.z; a3 += v.w;
            }
        }
        a0 += __shfl_xor(a0, 16); a0 += __shfl_xor(a0, 32);
        a1 += __shfl_xor(a1, 16); a1 += __shfl_xor(a1, 32);
        a2 += __shfl_xor(a2, 16); a2 += __shfl_xor(a2, 32);
        a3 += __shfl_xor(a3, 16); a3 += __shfl_xor(a3, 32);
        if (g == 0){
            float idg = inv_deg[node];
            float4 o = make_float4(a0*idg, a1*idg, a2*idg, a3*idg);
            *(float4*)&agg[(size_t)node*HIDC + qoff] = o;
        }
    }
}

// ---- per-tile GEMM kernels: 256 threads = 4 waves = 4 f-chunks of one
// 64-node tile. lane = node; fb via readfirstlane -> s_load weights
// (round-6 lesson: tid>>6 alone not provably uniform -> spill). ----

__global__ __launch_bounds__(256) void k_enc(
    const float* __restrict__ x,
    const float* __restrict__ w1, const float* __restrict__ b1,
    const float* __restrict__ w2, const float* __restrict__ b2,
    float* __restrict__ h)
{
    __shared__ float tl[64*64];
    int tile = blockIdx.x;
    int tid = threadIdx.x, lane = tid & 63;
    int fb = __builtin_amdgcn_readfirstlane((tid >> 6) * 16);
    int node = tile*64 + lane;
    int nc = (node < NN) ? node : (NN-1);     // x has exactly NN rows
    int sw = lane & 31;
    float out[16];
    #pragma unroll
    for (int j = 0; j < 16; j++) out[j] = b1[fb + j];
    gemm_acc<2>(x + (size_t)nc*INC, w1, fb, out);
    #pragma unroll
    for (int j = 0; j < 16; j++)
        tl[lane*64 + ((fb + j) ^ sw)] = gelu_exact(out[j]);
    __syncthreads();
    float o2[16];
    #pragma unroll
    for (int j = 0; j < 16; j++) o2[j] = b2[fb + j];
    #pragma unroll 4
    for (int k = 0; k < HIDC; k++){
        float ink = tl[lane*64 + (k ^ sw)];
        const float* wr = w2 + (size_t)k*HIDC + fb;
        #pragma unroll
        for (int j = 0; j < 16; j++) o2[j] = fmaf(ink, wr[j], o2[j]);
    }
    if (node < NN){
        float* dst = h + (size_t)node*HIDC + fb;
        #pragma unroll
        for (int j4 = 0; j4 < 4; j4++)
            *(float4*)(dst + j4*4) = make_float4(o2[j4*4+0], o2[j4*4+1],
                                                 o2[j4*4+2], o2[j4*4+3]);
    }
}

__global__ __launch_bounds__(256) void k_sage16(
    const float* __restrict__ h_in, const float* __restrict__ agg,
    const float* __restrict__ wl, const float* __restrict__ wr,
    const float* __restrict__ bias, float* __restrict__ h_out)
{
    int tile = blockIdx.x;
    int tid = threadIdx.x, lane = tid & 63;
    int fb = __builtin_amdgcn_readfirstlane((tid >> 6) * 16);
    int node = tile*64 + lane;                 // buffers padded to NPAD rows
    float out[16];
    #pragma unroll
    for (int j = 0; j < 16; j++) out[j] = bias[fb + j];
    gemm_acc<4>(agg  + (size_t)node*HIDC, wl, fb, out);
    gemm_acc<4>(h_in + (size_t)node*HIDC, wr, fb, out);
    if (node < NN){
        float* dst = h_out + (size_t)node*HIDC + fb;
        #pragma unroll
        for (int j4 = 0; j4 < 4; j4++){
            float4 o = make_float4(gelu_exact(out[j4*4+0]), gelu_exact(out[j4*4+1]),
                                   gelu_exact(out[j4*4+2]), gelu_exact(out[j4*4+3]));
            *(float4*)(dst + j4*4) = o;
        }
    }
}

__global__ __launch_bounds__(256) void k_dec1(
    const float* __restrict__ h, const float* __restrict__ w1,
    const float* __restrict__ b1, float* __restrict__ tbuf)
{
    int tile = blockIdx.x;
    int tid = threadIdx.x, lane = tid & 63;
    int fb = __builtin_amdgcn_readfirstlane((tid >> 6) * 16);
    int node = tile*64 + lane;
    float out[16];
    #pragma unroll
    for (int j = 0; j < 16; j++) out[j] = b1[fb + j];
    gemm_acc<4>(h + (size_t)node*HIDC, w1, fb, out);
    float* dst = tbuf + (size_t)node*HIDC + fb;   // tbuf padded: unmasked
    #pragma unroll
    for (int j4 = 0; j4 < 4; j4++){
        float4 o = make_float4(gelu_exact(out[j4*4+0]), gelu_exact(out[j4*4+1]),
                               gelu_exact(out[j4*4+2]), gelu_exact(out[j4*4+3]));
        *(float4*)(dst + j4*4) = o;
    }
}

__global__ __launch_bounds__(256) void k_dec2(
    const float* __restrict__ tbuf, const float* __restrict__ w2,
    const float* __restrict__ b2, float* __restrict__ out)
{
    int tile = blockIdx.x*4 + (threadIdx.x >> 6);
    if (tile >= NT_TILES) return;              // wave-uniform branch
    int lane = threadIdx.x & 63;
    int node = tile*64 + lane;
    const float* inrow = tbuf + (size_t)node*HIDC;
    float o[OUTC];
    #pragma unroll
    for (int j = 0; j < OUTC; j++) o[j] = b2[j];
    #pragma unroll 2
    for (int kc = 0; kc < 4; kc++){
        float4 q0 = *(const float4*)(inrow + kc*16 + 0);
        float4 q1 = *(const float4*)(inrow + kc*16 + 4);
        float4 q2 = *(const float4*)(inrow + kc*16 + 8);
        float4 q3 = *(const float4*)(inrow + kc*16 + 12);
        float in16[16] = {q0.x,q0.y,q0.z,q0.w, q1.x,q1.y,q1.z,q1.w,
                          q2.x,q2.y,q2.z,q2.w, q3.x,q3.y,q3.z,q3.w};
        #pragma unroll
        for (int kk = 0; kk < 16; kk++){
            const float* wr = w2 + (size_t)(kc*16+kk)*OUTC;
            #pragma unroll
            for (int j = 0; j < OUTC; j++)
                o[j] = fmaf(in16[kk], wr[j], o[j]);
        }
    }
    if (node < NN){
        *(float4*)(out + (size_t)node*OUTC + 0) = make_float4(o[0],o[1],o[2],o[3]);
        *(float4*)(out + (size_t)node*OUTC + 4) = make_float4(o[4],o[5],o[6],o[7]);
    }
}

extern "C" void kernel_launch(void* const* d_in, const int* in_sizes, int n_in,
                              void* d_out, int out_size, void* d_ws, size_t ws_size,
                              hipStream_t stream){
    const float* x      = (const float*)d_in[0];
    const int*   ei     = (const int*)  d_in[1];
    const float* enc_w1 = (const float*)d_in[2];
    const float* enc_b1 = (const float*)d_in[3];
    const float* enc_w2 = (const float*)d_in[4];
    const float* enc_b2 = (const float*)d_in[5];
    const float* sage_wl= (const float*)d_in[6];
    const float* sage_wr= (const float*)d_in[7];
    const float* sage_b = (const float*)d_in[8];
    const float* dec_w1 = (const float*)d_in[9];
    const float* dec_b1 = (const float*)d_in[10];
    const float* dec_w2 = (const float*)d_in[11];
    const float* dec_b2 = (const float*)d_in[12];
    float* out = (float*)d_out;

    char* ws = (char*)d_ws;
    size_t off = 0;
    auto alloc = [&](size_t bytes)->void*{
        void* p = ws + off; off = (off + bytes + 255) & ~(size_t)255; return p;
    };
    int*   deg      = (int*)  alloc((size_t)NN*4);
    int*   loc      = (int*)  alloc((size_t)NN*4);
    int*   bsum     = (int*)  alloc(64*4);
    int*   row_ptr  = (int*)  alloc((size_t)(NN+1)*4);
    int*   fill_pos = (int*)  alloc((size_t)NN*4);
    int*   col      = (int*)  alloc((size_t)NE*4);
    float* inv_deg  = (float*)alloc((size_t)NN*4);
    float* h0       = (float*)alloc((size_t)NPAD*HIDC*4);
    float* h1       = (float*)alloc((size_t)NPAD*HIDC*4);
    float* agg      = (float*)alloc((size_t)NPAD*HIDC*4);  // doubles as tbuf

    const int* srcv = ei;        // edge_index row 0
    const int* dstv = ei + NE;   // edge_index row 1

    hipMemsetAsync(deg, 0, (size_t)NN*4, stream);
    hipLaunchKernelGGL(k_hist_xcd, dim3(NXCD*PCH), dim3(256),  0, stream, dstv, deg);
    hipLaunchKernelGGL(k_scan1,    dim3(NB_SCAN),  dim3(1024), 0, stream, deg, loc, bsum);
    hipLaunchKernelGGL(k_scan2,    dim3(1),        dim3(64),   0, stream, bsum, h0, h1);
    hipLaunchKernelGGL(k_scan3,    dim3((NN+255)/256), dim3(256), 0, stream,
                       deg, loc, bsum, row_ptr, fill_pos, inv_deg);
    hipLaunchKernelGGL(k_fill_xcd, dim3(NXCD*PCH), dim3(256),  0, stream,
                       srcv, dstv, fill_pos, col);

    hipLaunchKernelGGL(k_enc, dim3(NT_TILES), dim3(256), 0, stream,
                       x, enc_w1, enc_b1, enc_w2, enc_b2, h0);

    const float* hin = h0; float* hout = h1;
    for (int l = 0; l < 3; l++){
        hipLaunchKernelGGL(k_agg, dim3(2048), dim3(256), 0, stream,
                           hin, row_ptr, col, inv_deg, agg);
        hipLaunchKernelGGL(k_sage16, dim3(NT_TILES), dim3(256), 0, stream,
                           hin, agg,
                           sage_wl + (size_t)l*HIDC*HIDC,
                           sage_wr + (size_t)l*HIDC*HIDC,
                           sage_b  + (size_t)l*HIDC,
                           hout);
        float* t = (float*)hin; hin = hout; hout = t;
    }

    hipLaunchKernelGGL(k_dec1, dim3(NT_TILES),       dim3(256), 0, stream,
                       hin, dec_w1, dec_b1, agg);
    hipLaunchKernelGGL(k_dec2, dim3((NT_TILES+3)/4), dim3(256), 0, stream,
                       agg, dec_w2, dec_b2, out);
}